// Round 16
// baseline (437.535 us; speedup 1.0000x reference)
//
#include <hip/hip_runtime.h>
#include <limits.h>

#define MAX_DEG 4
#define CSTRIDE 16   // ints; one counter per 64 B cache line to kill line-level
                     // serialization of atomics at the coherence point

// native clang vector type — __builtin_nontemporal_store rejects the
// HIP_vector_type class that hipcc's float4 is.
typedef float fx4 __attribute__((ext_vector_type(4)));

// ---------------------------------------------------------------------------
// Kernel 1: zero the padded per-node counter region (16 MB). d_ws is
// poisoned 0xAA before every timed launch, so this must run every call.
// int4 stores, one thread per 16 B.
// ---------------------------------------------------------------------------
__global__ __launch_bounds__(256) void k_init_cnt(int4* __restrict__ cnt4, int total4) {
    int i = blockIdx.x * blockDim.x + threadIdx.x;
    if (i < total4) cnt4[i] = make_int4(0, 0, 0, 0);
}

// ---------------------------------------------------------------------------
// Kernel 2: scatter incidences, one thread per EDGE, two independent
// returning atomics (sender + receiver). Counters are 64 B apart so the
// only atomic serialization left is the required 4-deep per-node chain
// (was 64-deep per cache line with packed counters — suspected cause of
// the ~85 us scatter inferred from rounds 4/15). Slot order within a node
// is atomic-arbitrary; the write kernel's sorting network restores the
// reference's ascending-edge-index rank. Self-loops count once (matches
// the reference's sentinel routing). Slots beyond MAX_DEG are dropped
// (benchmark graph has degree exactly 4).
// ---------------------------------------------------------------------------
__global__ __launch_bounds__(256) void k_scatter(const int* __restrict__ senders,
                                                 const int* __restrict__ receivers,
                                                 int* __restrict__ cnt,
                                                 int* __restrict__ slots,
                                                 int E) {
    int e = blockIdx.x * blockDim.x + threadIdx.x;
    if (e >= E) return;
    int s = senders[e];
    int r = receivers[e];
    int p = atomicAdd(&cnt[(size_t)s * CSTRIDE], 1);
    if (p < MAX_DEG) slots[(size_t)s * MAX_DEG + p] = e;
    if (r != s) {
        int q = atomicAdd(&cnt[(size_t)r * CSTRIDE], 1);
        if (q < MAX_DEG) slots[(size_t)r * MAX_DEG + q] = e;
    }
}

__device__ __forceinline__ void cswap(int& a, int& b) {
    int lo = min(a, b), hi = max(a, b);
    a = lo; b = hi;
}

// ---------------------------------------------------------------------------
// Kernel 3 (hot): fused sort + gather + write. One thread per output
// float4; one 64-lane wave per node (4 slots x 16 float4s at F=64). Loads
// the node's count (wave-uniform 4 B -> L1 broadcast) and slot quad (one
// dwordx4, wave-uniform), masks unfilled slots to INT_MAX, sorts ascending
// with a 5-compare network (reference's ascending-edge-index rank +
// pad-to-4), selects this lane's edge via a static cndmask chain, gathers
// edges[e] (16-lane contiguous 256 B segments), zeros for padding.
// Output store: NON-TEMPORAL (write-once 256 MB stream) so it does not
// evict the 2x-reused edges lines from L2. Store index == flat thread
// index -> perfectly coalesced 16 B/lane. ~390 MB total traffic -> ~60 us
// at 6.4 TB/s, believed at BW floor.
// ---------------------------------------------------------------------------
template <int FQ>
__global__ __launch_bounds__(256) void k_sort_write(const fx4* __restrict__ edges,
                                                    const int* __restrict__ cnt,
                                                    const int4* __restrict__ slots4,
                                                    fx4* __restrict__ out,
                                                    int totalQ) {
    int idx = blockIdx.x * blockDim.x + threadIdx.x;
    if (idx >= totalQ) return;
    int n   = idx / (MAX_DEG * FQ);          // folds to shift for FQ=16
    int off = idx - n * (MAX_DEG * FQ);
    int s   = off / FQ;
    int q   = off - s * FQ;

    int c = min(cnt[(size_t)n * CSTRIDE], MAX_DEG);
    int4 sl = slots4[n];
    const int INF = INT_MAX;
    int v0 = (c > 0) ? sl.x : INF;
    int v1 = (c > 1) ? sl.y : INF;
    int v2 = (c > 2) ? sl.z : INF;
    int v3 = (c > 3) ? sl.w : INF;
    cswap(v0, v1); cswap(v2, v3); cswap(v0, v2); cswap(v1, v3); cswap(v1, v2);
    int e = (s == 0) ? v0 : (s == 1) ? v1 : (s == 2) ? v2 : v3;

    fx4 v = (fx4)(0.f);
    if (e != INF) v = edges[(size_t)e * FQ + q];
    __builtin_nontemporal_store(v, &out[(size_t)idx]);
}

// ---------------------------------------------------------------------------
// Generic fallback (F not divisible by 4) — not hit by the benchmark (F=64).
// ---------------------------------------------------------------------------
__global__ __launch_bounds__(256) void k_write_scalar(const float* __restrict__ edges,
                                                      const int* __restrict__ cnt,
                                                      const int4* __restrict__ slots4,
                                                      float* __restrict__ out,
                                                      int total, int F) {
    int idx = blockIdx.x * blockDim.x + threadIdx.x;
    if (idx >= total) return;
    int row = idx / F;
    int f   = idx - row * F;
    int n   = row >> 2;
    int s   = row & 3;
    int c = min(cnt[(size_t)n * CSTRIDE], MAX_DEG);
    int4 sl = slots4[n];
    const int INF = INT_MAX;
    int v0 = (c > 0) ? sl.x : INF;
    int v1 = (c > 1) ? sl.y : INF;
    int v2 = (c > 2) ? sl.z : INF;
    int v3 = (c > 3) ? sl.w : INF;
    cswap(v0, v1); cswap(v2, v3); cswap(v0, v2); cswap(v1, v3); cswap(v1, v2);
    int e = (s == 0) ? v0 : (s == 1) ? v1 : (s == 2) ? v2 : v3;
    out[(size_t)idx] = (e != INF) ? edges[(size_t)e * F + f] : 0.f;
}

extern "C" void kernel_launch(void* const* d_in, const int* in_sizes, int n_in,
                              void* d_out, int out_size, void* d_ws, size_t ws_size,
                              hipStream_t stream) {
    // inputs (setup_inputs order): nodes [N,F] f32 (unused), edges [E,F] f32,
    //                              senders [E] i32, receivers [E] i32
    const float* edges     = (const float*)d_in[1];
    const int*   senders   = (const int*)d_in[2];
    const int*   receivers = (const int*)d_in[3];
    float*       out       = (float*)d_out;

    const int E = in_sizes[2];
    const int F = in_sizes[1] / E;
    const int N = in_sizes[0] / F;

    // ws layout: slots[N*4] ints (16 B-aligned quads, 4 MB), then
    // cnt[N*CSTRIDE] ints (64 B-strided counters, 16 MB). 20 MB total.
    int* slots = (int*)d_ws;
    int* cnt   = slots + (size_t)N * MAX_DEG;

    const int total4 = N * CSTRIDE / 4;   // int4 count of the cnt region
    k_init_cnt<<<(total4 + 255) / 256, 256, 0, stream>>>((int4*)cnt, total4);
    k_scatter<<<(E + 255) / 256, 256, 0, stream>>>(senders, receivers, cnt, slots, E);

    if (F == 64) {
        const int totalQ = N * MAX_DEG * 16;
        k_sort_write<16><<<(totalQ + 255) / 256, 256, 0, stream>>>(
            (const fx4*)edges, cnt, (const int4*)slots, (fx4*)out, totalQ);
    } else {
        const int total = N * MAX_DEG * F;
        k_write_scalar<<<(total + 255) / 256, 256, 0, stream>>>(
            edges, cnt, (const int4*)slots, out, total, F);
    }
}

// Round 17
// 403.951 us; speedup vs baseline: 1.0831x; 1.0831x over previous
//
#include <hip/hip_runtime.h>
#include <limits.h>

#define MAX_DEG 4

// native clang vector type — __builtin_nontemporal_store rejects the
// HIP_vector_type class that hipcc's float4 is.
typedef float fx4 __attribute__((ext_vector_type(4)));

// ---------------------------------------------------------------------------
// Kernel 1: init workspace (d_ws is poisoned 0xAA before every timed
// launch). Pre-fills the slot table with INT_MAX (= empty sentinel = sort
// padding) and zeroes the PACKED per-node counters. Packed counters won:
// round-16's 64 B-padded counters cost +43 us (16x more lines touched);
// L2 atomic units serialize same-line ops cheaply in place.
// ---------------------------------------------------------------------------
__global__ __launch_bounds__(256) void k_init(int4* __restrict__ slots4,
                                              int* __restrict__ cnt, int N) {
    int i = blockIdx.x * blockDim.x + threadIdx.x;
    if (i < N) {
        slots4[i] = make_int4(INT_MAX, INT_MAX, INT_MAX, INT_MAX);
        cnt[i] = 0;
    }
}

// ---------------------------------------------------------------------------
// Kernel 2 (round-15 winner, measured ~57 us): one thread per INCIDENCE
// (2E threads), exactly one independent returning atomicAdd each on packed
// counters. Threads [0,E) = sender incidences; [E,2E) = receiver
// incidences, skipping self-loops (counted once, matching the reference's
// sentinel routing). Slot order is atomic-arbitrary; the write kernel's
// sorting network restores ascending-edge-index rank. Slots beyond
// MAX_DEG dropped (benchmark graph has degree exactly 4).
// ---------------------------------------------------------------------------
__global__ __launch_bounds__(256) void k_scatter(const int* __restrict__ senders,
                                                 const int* __restrict__ receivers,
                                                 int* __restrict__ cnt,
                                                 int* __restrict__ slots,
                                                 int E) {
    int t = blockIdx.x * blockDim.x + threadIdx.x;
    if (t >= 2 * E) return;
    int e, n;
    if (t < E) {
        e = t;
        n = senders[t];
    } else {
        e = t - E;
        n = receivers[e];
        if (n == senders[e]) return;   // self-loop counted once
    }
    int p = atomicAdd(&cnt[n], 1);
    if (p < MAX_DEG) slots[n * MAX_DEG + p] = e;
}

__device__ __forceinline__ void cswap(int& a, int& b) {
    int lo = min(a, b), hi = max(a, b);
    a = lo; b = hi;
}

// ---------------------------------------------------------------------------
// Kernel 3 (hot): fused sort + gather + write. One thread per output
// float4; one 64-lane wave per node. No cnt read: unfilled slots are
// INT_MAX from init and sink to the back of the 5-compare network.
// XCD-chunked block swizzle (bijective when gridDim%8==0): physical
// dispatch round-robins XCDs, so logical = (bid%8)*(nwg/8) + bid/8 gives
// each XCD a contiguous node range -> the 2x-reused edge rows (nodes n,
// n+1 share edge n) hit the same XCD's L2 instead of bouncing via L3.
// Output: non-temporal coalesced 16 B/lane stores (write-once 256 MB).
// ---------------------------------------------------------------------------
template <int FQ>
__global__ __launch_bounds__(256) void k_sort_write(const fx4* __restrict__ edges,
                                                    const int4* __restrict__ slots4,
                                                    fx4* __restrict__ out,
                                                    int totalQ) {
    int nwg = gridDim.x;
    int bid = blockIdx.x;
    int lbid = ((nwg & 7) == 0) ? ((bid & 7) * (nwg >> 3) + (bid >> 3)) : bid;
    int idx = lbid * blockDim.x + threadIdx.x;
    if (idx >= totalQ) return;
    int n   = idx / (MAX_DEG * FQ);          // folds to shift for FQ=16
    int off = idx - n * (MAX_DEG * FQ);
    int s   = off / FQ;
    int q   = off - s * FQ;

    int4 sl = slots4[n];
    int v0 = sl.x, v1 = sl.y, v2 = sl.z, v3 = sl.w;
    cswap(v0, v1); cswap(v2, v3); cswap(v0, v2); cswap(v1, v3); cswap(v1, v2);
    int e = (s == 0) ? v0 : (s == 1) ? v1 : (s == 2) ? v2 : v3;

    fx4 v = (fx4)(0.f);
    if (e != INT_MAX) v = edges[(size_t)e * FQ + q];
    __builtin_nontemporal_store(v, &out[(size_t)idx]);
}

// ---------------------------------------------------------------------------
// Generic fallback (F not divisible by 4) — not hit by the benchmark (F=64).
// ---------------------------------------------------------------------------
__global__ __launch_bounds__(256) void k_write_scalar(const float* __restrict__ edges,
                                                      const int4* __restrict__ slots4,
                                                      float* __restrict__ out,
                                                      int total, int F) {
    int idx = blockIdx.x * blockDim.x + threadIdx.x;
    if (idx >= total) return;
    int row = idx / F;
    int f   = idx - row * F;
    int n   = row >> 2;
    int s   = row & 3;
    int4 sl = slots4[n];
    int v0 = sl.x, v1 = sl.y, v2 = sl.z, v3 = sl.w;
    cswap(v0, v1); cswap(v2, v3); cswap(v0, v2); cswap(v1, v3); cswap(v1, v2);
    int e = (s == 0) ? v0 : (s == 1) ? v1 : (s == 2) ? v2 : v3;
    out[(size_t)idx] = (e != INT_MAX) ? edges[(size_t)e * F + f] : 0.f;
}

extern "C" void kernel_launch(void* const* d_in, const int* in_sizes, int n_in,
                              void* d_out, int out_size, void* d_ws, size_t ws_size,
                              hipStream_t stream) {
    // inputs (setup_inputs order): nodes [N,F] f32 (unused), edges [E,F] f32,
    //                              senders [E] i32, receivers [E] i32
    const float* edges     = (const float*)d_in[1];
    const int*   senders   = (const int*)d_in[2];
    const int*   receivers = (const int*)d_in[3];
    float*       out       = (float*)d_out;

    const int E = in_sizes[2];
    const int F = in_sizes[1] / E;
    const int N = in_sizes[0] / F;

    // ws layout: slots[N*4] ints (16 B-aligned quads, 4 MB), cnt[N] (1 MB).
    int* slots = (int*)d_ws;
    int* cnt   = slots + (size_t)N * MAX_DEG;

    k_init<<<(N + 255) / 256, 256, 0, stream>>>((int4*)slots, cnt, N);
    k_scatter<<<(2 * E + 255) / 256, 256, 0, stream>>>(senders, receivers, cnt, slots, E);

    if (F == 64) {
        const int totalQ = N * MAX_DEG * 16;
        k_sort_write<16><<<(totalQ + 255) / 256, 256, 0, stream>>>(
            (const fx4*)edges, (const int4*)slots, (fx4*)out, totalQ);
    } else {
        const int total = N * MAX_DEG * F;
        k_write_scalar<<<(total + 255) / 256, 256, 0, stream>>>(
            edges, (const int4*)slots, out, total, F);
    }
}